// Round 2
// baseline (307.505 us; speedup 1.0000x reference)
//
#include <hip/hip_runtime.h>
#include <hip/hip_bf16.h>

#define HID 128

typedef __attribute__((ext_vector_type(8))) short short8;   // 8 x bf16 (4 VGPRs)
typedef __attribute__((ext_vector_type(4))) float f32x4;    // MFMA C/D

static __device__ __forceinline__ short f2bf(float x) {
    __hip_bfloat16 h = __float2bfloat16(x);   // RNE
    return *reinterpret_cast<short*>(&h);
}

// ---------------------------------------------------------------------------
// Prep: one stage of the collapsed weight chain (ALL fp32 inputs).
//   C[i][j] = sum_k A[i][k] * B[k][j];  cout[i] = sum_k A[i][k]*cin[k] + badd[i]
// final_stage: write Mb = bf16(I + 0.5*C) and cout = 0.5*(chain).
// grid = 128 blocks (i), block = 128 threads (j). ~2 MFLOP/stage — noise.
// ---------------------------------------------------------------------------
__global__ void prep_stage(const float* __restrict__ A,
                           const float* __restrict__ B,
                           const float* __restrict__ cin,
                           const float* __restrict__ badd,
                           float* __restrict__ Cf,
                           __hip_bfloat16* __restrict__ Mb, int final_stage,
                           float* __restrict__ cout)
{
    __shared__ float arow[HID];
    const int i = blockIdx.x;
    const int j = threadIdx.x;
    arow[j] = A[i * HID + j];
    __syncthreads();

    float s = 0.f;
    #pragma unroll 8
    for (int k = 0; k < HID; ++k) s += arow[k] * B[k * HID + j];

    if (final_stage) {
        float m = ((i == j) ? 1.0f : 0.0f) + 0.5f * s;   // fold residual: I + 0.5*M
        Mb[i * HID + j] = __float2bfloat16(m);
    } else {
        Cf[i * HID + j] = s;
    }

    if (j == 0) {   // bias chain
        float t = 0.f;
        for (int k = 0; k < HID; ++k) t += arow[k] * cin[k];
        t += badd[i];
        cout[i] = final_stage ? 0.5f * t : t;
    }
}

// ---------------------------------------------------------------------------
// Main: out[e][:] = ea[e][:] @ M'^T + c'     (fp32 in, fp32 out)
// One wave per 16-edge tile, 16x16x32 bf16 MFMA; A cast fp32->bf16 in-register.
// All of M' (32 KB bf16) resident in VGPRs per wave; no LDS, no barriers.
// ---------------------------------------------------------------------------
__global__ __launch_bounds__(256) void edge_gemm(
    const float* __restrict__ ea,
    const __hip_bfloat16* __restrict__ Mb,   // [128][128] bf16 row-major: M'[n][k]
    const float* __restrict__ cvec,          // [128] fp32 = 0.5*c
    float* __restrict__ out,
    int E, int numTiles)
{
    const int lane = threadIdx.x & 63;
    const int wv   = threadIdx.x >> 6;
    const int q    = lane >> 4;       // 0..3
    const int c    = lane & 15;       // 0..15

    // B fragment: lane holds B[k = kk*32 + q*8 + j][n = c] = M'[n][k]
    short8 bfrag[8][4];
    #pragma unroll
    for (int nt = 0; nt < 8; ++nt) {
        const __hip_bfloat16* bp = Mb + (size_t)(nt * 16 + c) * HID + q * 8;
        #pragma unroll
        for (int kk = 0; kk < 4; ++kk)
            bfrag[nt][kk] = *reinterpret_cast<const short8*>(bp + kk * 32);
    }
    float cv[8];
    #pragma unroll
    for (int nt = 0; nt < 8; ++nt) cv[nt] = cvec[nt * 16 + c];

    const int slot   = blockIdx.x * 4 + wv;
    const int stride = gridDim.x * 4;

    for (int t = slot; t < numTiles; t += stride) {
        const int edge0 = t * 16;

        // A fragment: lane holds A[m = c][k = kk*32 + q*8 + j], fp32 -> bf16.
        int rowA = edge0 + c;
        if (rowA > E - 1) rowA = E - 1;
        const float* ap = ea + (size_t)rowA * HID + q * 8;
        short8 afrag[4];
        #pragma unroll
        for (int kk = 0; kk < 4; ++kk) {
            const float4 f0 = *reinterpret_cast<const float4*>(ap + kk * 32);
            const float4 f1 = *reinterpret_cast<const float4*>(ap + kk * 32 + 4);
            short8 a;
            a[0] = f2bf(f0.x); a[1] = f2bf(f0.y); a[2] = f2bf(f0.z); a[3] = f2bf(f0.w);
            a[4] = f2bf(f1.x); a[5] = f2bf(f1.y); a[6] = f2bf(f1.z); a[7] = f2bf(f1.w);
            afrag[kk] = a;
        }

        f32x4 acc[8];
        #pragma unroll
        for (int nt = 0; nt < 8; ++nt) acc[nt] = (f32x4){0.f, 0.f, 0.f, 0.f};

        #pragma unroll
        for (int kk = 0; kk < 4; ++kk) {
            #pragma unroll
            for (int nt = 0; nt < 8; ++nt)
                acc[nt] = __builtin_amdgcn_mfma_f32_16x16x32_bf16(
                    afrag[kk], bfrag[nt][kk], acc[nt], 0, 0, 0);
        }

        // C/D layout: D[row = q*4 + r][col = c] in acc[nt][r].
        #pragma unroll
        for (int r = 0; r < 4; ++r) {
            const int row = edge0 + q * 4 + r;
            if (row < E) {
                float* op = out + (size_t)row * HID + c;
                #pragma unroll
                for (int nt = 0; nt < 8; ++nt)
                    op[nt * 16] = acc[nt][r] + cv[nt];
            }
        }
    }
}

// ---------------------------------------------------------------------------
// Inputs (setup_inputs order, ALL float32; edge_index int — unused):
//  0 edge_attr [E*128]  1 node_features  2 regime_probs
//  3 Wq 4 bq 5 Wk 6 bk                 (DEAD: softmax over singleton = 1)
//  7 Wv 8 bv  9 W_in [3*128,128] 10 b_in [384] (only value third live)
// 11 W_mo 12 b_mo 13 Wo 14 bo 15 edge_index (DEAD)
// out = ea + 0.5*(ea @ (Wo@W_mo@Wiv@Wv)^T + c) = ea @ (I+0.5M)^T + 0.5c
// ---------------------------------------------------------------------------
extern "C" void kernel_launch(void* const* d_in, const int* in_sizes, int n_in,
                              void* d_out, int out_size, void* d_ws, size_t ws_size,
                              hipStream_t stream) {
    const float* ea   = (const float*)d_in[0];
    const float* Wv   = (const float*)d_in[7];
    const float* bv   = (const float*)d_in[8];
    const float* W_in = (const float*)d_in[9];
    const float* b_in = (const float*)d_in[10];
    const float* W_mo = (const float*)d_in[11];
    const float* b_mo = (const float*)d_in[12];
    const float* Wo   = (const float*)d_in[13];
    const float* bo   = (const float*)d_in[14];
    const float* Wiv  = W_in + 2 * HID * HID;   // value third of packed in-proj
    const float* biv  = b_in + 2 * HID;

    char* ws = (char*)d_ws;
    float*          P1 = (float*)(ws);                    // 64 KB
    float*          P2 = (float*)(ws + 65536);            // 64 KB
    __hip_bfloat16* Mb = (__hip_bfloat16*)(ws + 131072);  // 32 KB
    float*          c1 = (float*)(ws + 163840);           // 512 B
    float*          c2 = (float*)(ws + 164352);           // 512 B
    float*          cv = (float*)(ws + 164864);           // 512 B

    const int E = in_sizes[0] / HID;
    const int numTiles = (E + 15) / 16;

    // M' = I + 0.5*(Wo @ W_mo @ Wiv @ Wv); c' = 0.5*(Wo(W_mo(Wiv bv + biv)+b_mo)+bo)
    prep_stage<<<dim3(HID), dim3(HID), 0, stream>>>(Wiv,  Wv, bv, biv,  P1, nullptr, 0, c1);
    prep_stage<<<dim3(HID), dim3(HID), 0, stream>>>(W_mo, P1, c1, b_mo, P2, nullptr, 0, c2);
    prep_stage<<<dim3(HID), dim3(HID), 0, stream>>>(Wo,   P2, c2, bo,   nullptr, Mb, 1, cv);

    edge_gemm<<<dim3(2048), dim3(256), 0, stream>>>(
        ea, Mb, cv, (float*)d_out, E, numTiles);
}

// Round 3
// 297.875 us; speedup vs baseline: 1.0323x; 1.0323x over previous
//
#include <hip/hip_runtime.h>
#include <hip/hip_bf16.h>

#define HID 128

typedef __attribute__((ext_vector_type(8))) short short8;   // 8 x bf16 (4 VGPRs)
typedef __attribute__((ext_vector_type(4))) float f32x4;    // MFMA C/D

static __device__ __forceinline__ short f2bf(float x) {
    __hip_bfloat16 h = __float2bfloat16(x);   // RNE
    return *reinterpret_cast<short*>(&h);
}

// ---------------------------------------------------------------------------
// K1: the two INDEPENDENT 128x128 products in one launch, plus the bias
// chain parallelized over its 128 outputs (R2's serial j==0 loop was ~70 us
// of block-tail per stage — the real cost of the 307 us total).
//   blocks 0..127   : P_left  = Wo  @ W_mo      (row b)
//   blocks 128..255 : P_right = Wiv @ Wv        (row b-128)
//   block  256      : cv = 0.5*(Wo@(W_mo@(Wiv@bv + biv) + b_mo) + bo)
// ---------------------------------------------------------------------------
__global__ void prep_products(const float* __restrict__ Wo,
                              const float* __restrict__ W_mo,
                              const float* __restrict__ Wiv,
                              const float* __restrict__ Wv,
                              const float* __restrict__ bv,
                              const float* __restrict__ biv,
                              const float* __restrict__ b_mo,
                              const float* __restrict__ bo,
                              float* __restrict__ Pl,
                              float* __restrict__ Pr,
                              float* __restrict__ cv)
{
    const int j = threadIdx.x;
    const int b = blockIdx.x;
    __shared__ float sh[HID];

    if (b < 256) {
        const float* A = (b < 128) ? Wo   : Wiv;
        const float* B = (b < 128) ? W_mo : Wv;
        float*       C = (b < 128) ? Pl   : Pr;
        const int i = b & 127;
        sh[j] = A[i * HID + j];
        __syncthreads();
        float s = 0.f;
        #pragma unroll 16
        for (int k = 0; k < HID; ++k) s += sh[k] * B[k * HID + j];
        C[i * HID + j] = s;
    } else {
        // bias chain: 3 matvecs, each parallel over the 128 outputs.
        sh[j] = bv[j];
        __syncthreads();
        float t = biv[j];
        #pragma unroll 16
        for (int k = 0; k < HID; ++k) t += Wiv[j * HID + k] * sh[k];
        __syncthreads(); sh[j] = t; __syncthreads();
        t = b_mo[j];
        #pragma unroll 16
        for (int k = 0; k < HID; ++k) t += W_mo[j * HID + k] * sh[k];
        __syncthreads(); sh[j] = t; __syncthreads();
        t = bo[j];
        #pragma unroll 16
        for (int k = 0; k < HID; ++k) t += Wo[j * HID + k] * sh[k];
        cv[j] = 0.5f * t;
    }
}

// ---------------------------------------------------------------------------
// K2: M' = bf16( I + 0.5 * P_left @ P_right )   (row-major [n][k])
// ---------------------------------------------------------------------------
__global__ void prep_final(const float* __restrict__ Pl,
                           const float* __restrict__ Pr,
                           __hip_bfloat16* __restrict__ Mb)
{
    const int i = blockIdx.x, j = threadIdx.x;
    __shared__ float sh[HID];
    sh[j] = Pl[i * HID + j];
    __syncthreads();
    float s = 0.f;
    #pragma unroll 16
    for (int k = 0; k < HID; ++k) s += sh[k] * Pr[k * HID + j];
    Mb[i * HID + j] = __float2bfloat16(((i == j) ? 1.0f : 0.0f) + 0.5f * s);
}

// ---------------------------------------------------------------------------
// Main: out[e][:] = ea[e][:] @ M'^T + cv      (fp32 in/out, bf16 MFMA)
//
// Role-swapped vs R2: M' is the A-operand (features = M-dim, in registers),
// edges are the B-operand (N-dim, across lanes). C/D layout then gives each
// lane 4 CONTIGUOUS floats of one edge row per acc register -> dwordx4
// nontemporal stores (R2 had 32 scattered dword stores/tile -> vmcnt(0)
// store-drain every tile).
//
// Each of the block's 4 waves owns 32 output cols (2 n-tiles): M'-frags are
// only 32 VGPRs/wave; the 4 waves load the SAME edge bytes (L1 dedup).
// Next tile's loads are issued before this tile's stores, so the load-wait
// is vmcnt(stores) — stores never block the pipeline.
// ---------------------------------------------------------------------------
__global__ __launch_bounds__(256) void edge_gemm(
    const float* __restrict__ ea,
    const __hip_bfloat16* __restrict__ Mb,   // [128][128] bf16: M'[n][k]
    const float* __restrict__ cvec,          // [128] = 0.5*c
    float* __restrict__ out,
    int E, int numTiles)
{
    const int lane  = threadIdx.x & 63;
    const int wv    = threadIdx.x >> 6;
    const int q     = lane >> 4;      // 0..3
    const int c     = lane & 15;      // 0..15
    const int ncol0 = wv * 32;        // this wave's 32 output cols

    // A-frag: lane (q,c) holds M'[ncol0 + nt*16 + c][kk*32 + q*8 .. +7]
    short8 Mfrag[2][4];
    #pragma unroll
    for (int nt = 0; nt < 2; ++nt) {
        const __hip_bfloat16* mp = Mb + (size_t)(ncol0 + nt * 16 + c) * HID + q * 8;
        #pragma unroll
        for (int kk = 0; kk < 4; ++kk)
            Mfrag[nt][kk] = *reinterpret_cast<const short8*>(mp + kk * 32);
    }
    // Bias as accumulator init: acc[nt][r] <-> out col ncol0 + nt*16 + q*4 + r
    f32x4 cvp[2];
    #pragma unroll
    for (int nt = 0; nt < 2; ++nt)
        cvp[nt] = *reinterpret_cast<const f32x4*>(cvec + ncol0 + nt * 16 + q * 4);

    int t = blockIdx.x;
    if (t >= numTiles) return;

    // Preload tile t's edge data (raw fp32; cast to bf16 when consumed).
    float4 raw[8];
    {
        int row = t * 16 + c; if (row > E - 1) row = E - 1;
        const float* ap = ea + (size_t)row * HID + q * 8;
        #pragma unroll
        for (int kk = 0; kk < 4; ++kk) {
            raw[2 * kk]     = *reinterpret_cast<const float4*>(ap + kk * 32);
            raw[2 * kk + 1] = *reinterpret_cast<const float4*>(ap + kk * 32 + 4);
        }
    }

    while (true) {
        const int edge0 = t * 16;
        const int tn    = t + gridDim.x;

        // B-frag: lane (q,c) holds ea[edge0+c][kk*32 + q*8 .. +7] as bf16.
        short8 bfrag[4];
        #pragma unroll
        for (int kk = 0; kk < 4; ++kk) {
            const float4 f0 = raw[2 * kk], f1 = raw[2 * kk + 1];
            short8 v;
            v[0] = f2bf(f0.x); v[1] = f2bf(f0.y); v[2] = f2bf(f0.z); v[3] = f2bf(f0.w);
            v[4] = f2bf(f1.x); v[5] = f2bf(f1.y); v[6] = f2bf(f1.z); v[7] = f2bf(f1.w);
            bfrag[kk] = v;
        }

        // Software prefetch of tile tn (issued BEFORE this tile's stores).
        if (tn < numTiles) {
            int row = tn * 16 + c; if (row > E - 1) row = E - 1;
            const float* ap = ea + (size_t)row * HID + q * 8;
            #pragma unroll
            for (int kk = 0; kk < 4; ++kk) {
                raw[2 * kk]     = *reinterpret_cast<const float4*>(ap + kk * 32);
                raw[2 * kk + 1] = *reinterpret_cast<const float4*>(ap + kk * 32 + 4);
            }
        }

        f32x4 acc[2] = { cvp[0], cvp[1] };
        #pragma unroll
        for (int kk = 0; kk < 4; ++kk) {
            acc[0] = __builtin_amdgcn_mfma_f32_16x16x32_bf16(Mfrag[0][kk], bfrag[kk], acc[0], 0, 0, 0);
            acc[1] = __builtin_amdgcn_mfma_f32_16x16x32_bf16(Mfrag[1][kk], bfrag[kk], acc[1], 0, 0, 0);
        }

        // acc[nt] = out[edge0+c][ncol0 + nt*16 + q*4 .. +3]  — contiguous.
        const int orow = edge0 + c;
        if (orow < E) {
            float* op = out + (size_t)orow * HID + ncol0 + q * 4;
            __builtin_nontemporal_store(acc[0], reinterpret_cast<f32x4*>(op));
            __builtin_nontemporal_store(acc[1], reinterpret_cast<f32x4*>(op + 16));
        }

        if (tn >= numTiles) break;
        t = tn;
    }
}

// ---------------------------------------------------------------------------
// Inputs (setup_inputs order, all float32; edge_index int64 — DEAD):
//  0 edge_attr  1 node_features(DEAD)  2 regime_probs(DEAD)
//  3 Wq 4 bq 5 Wk 6 bk (DEAD: softmax over singleton seq = 1 => att = v2)
//  7 Wv 8 bv  9 W_in[3*128,128] 10 b_in[384] (only value third live)
// 11 W_mo 12 b_mo 13 Wo 14 bo 15 edge_index(DEAD)
// out = ea @ (I + 0.5*Wo@W_mo@Wiv@Wv)^T + 0.5*c
// ---------------------------------------------------------------------------
extern "C" void kernel_launch(void* const* d_in, const int* in_sizes, int n_in,
                              void* d_out, int out_size, void* d_ws, size_t ws_size,
                              hipStream_t stream) {
    const float* Wv   = (const float*)d_in[7];
    const float* bv   = (const float*)d_in[8];
    const float* W_in = (const float*)d_in[9];
    const float* b_in = (const float*)d_in[10];
    const float* W_mo = (const float*)d_in[11];
    const float* b_mo = (const float*)d_in[12];
    const float* Wo   = (const float*)d_in[13];
    const float* bo   = (const float*)d_in[14];
    const float* Wiv  = W_in + 2 * HID * HID;   // value third of packed in-proj
    const float* biv  = b_in + 2 * HID;

    char* ws = (char*)d_ws;
    float*          Pl = (float*)(ws);                    // 64 KB
    float*          Pr = (float*)(ws + 65536);            // 64 KB
    __hip_bfloat16* Mb = (__hip_bfloat16*)(ws + 131072);  // 32 KB
    float*          cv = (float*)(ws + 163840);           // 512 B

    const int E = in_sizes[0] / HID;
    const int numTiles = (E + 15) / 16;

    prep_products<<<dim3(257), dim3(HID), 0, stream>>>(
        Wo, W_mo, Wiv, Wv, bv, biv, b_mo, bo, Pl, Pr, cv);
    prep_final<<<dim3(HID), dim3(HID), 0, stream>>>(Pl, Pr, Mb);

    edge_gemm<<<dim3(1024), dim3(256), 0, stream>>>(
        (const float*)d_in[0], Mb, cv, (float*)d_out, E, numTiles);
}